// Round 5
// baseline (120.826 us; speedup 1.0000x reference)
//
#include <hip/hip_runtime.h>

// AttentionNet N=128, a1=a2=64, f=2 — R5: ONE fused kernel, grid N, block 1024.
// x held in registers for the whole kernel; per stage: p/q = exp2 tiles into
// reused LDS (factorized sigmoid: sigma = 1/(1 + p[j,k]*q[i,k])), then
// register-resident inner loop (readlane + v_fma + v_rcp + add), in-LDS
// softmax between stages. No global round-trips, no extra launches.

constexpr int A   = 64;
constexpr int PAD = 65;   // bank = (j+k)%32 -> 2-way aliasing = free (m136)
constexpr float L2E  = 1.4426950408889634f;
constexpr float EPSF = 1e-6f;

__device__ __forceinline__ float bcast(float v, int srcLane) {
    return __int_as_float(__builtin_amdgcn_readlane(__float_as_int(v), srcLane));
}
__device__ __forceinline__ float rcpf(float v) { return __builtin_amdgcn_rcpf(v); }
__device__ __forceinline__ float ex2(float v)  { return __builtin_amdgcn_exp2f(v); }

// c-row stats for rows row0..row0+3 (lane <-> column j); lane0 writes mbuf[row].
__device__ __forceinline__ void att4(const float* __restrict__ prow,
                                     const float* __restrict__ qrow,
                                     int row0, int lane, float* __restrict__ mbuf)
{
    float acc0 = 0.f, acc1 = 0.f, acc2 = 0.f, acc3 = 0.f;
#pragma unroll 1
    for (int c = 0; c < 4; ++c) {
        float pk[16], qk[16];
#pragma unroll
        for (int t = 0; t < 16; ++t) {
            pk[t] = prow[c * 16 + t];
            qk[t] = qrow[c * 16 + t];
        }
#pragma unroll
        for (int t = 0; t < 16; ++t) {
            float q0 = bcast(qk[t], row0);
            float q1 = bcast(qk[t], row0 + 1);
            float q2 = bcast(qk[t], row0 + 2);
            float q3 = bcast(qk[t], row0 + 3);
            acc0 += rcpf(fmaf(pk[t], q0, 1.0f));
            acc1 += rcpf(fmaf(pk[t], q1, 1.0f));
            acc2 += rcpf(fmaf(pk[t], q2, 1.0f));
            acc3 += rcpf(fmaf(pk[t], q3, 1.0f));
        }
    }
    float s[4] = {acc0, acc1, acc2, acc3};
    float m[4] = {acc0, acc1, acc2, acc3};
#pragma unroll
    for (int off = 1; off < 64; off <<= 1) {
#pragma unroll
        for (int r = 0; r < 4; ++r) {
            s[r] += __shfl_xor(s[r], off, 64);
            m[r] = fmaxf(m[r], __shfl_xor(m[r], off, 64));
        }
    }
    if (lane == 0) {
#pragma unroll
        for (int r = 0; r < 4; ++r)   // acc = 64*c: mean=s/4096, max=m/64
            mbuf[row0 + r] = (s[r] * (1.0f / 4096.0f)) / (m[r] * (1.0f / 64.0f) + EPSF);
    }
}

__device__ __forceinline__ float softmax64(float m, float sharp, float th, bool last)
{
    float v = fmaxf(0.f, m * sharp + th);
    float mx = v;
#pragma unroll
    for (int off = 1; off < 64; off <<= 1) mx = fmaxf(mx, __shfl_xor(mx, off, 64));
    float e = __expf(v - mx);
    float s = e;
#pragma unroll
    for (int off = 1; off < 64; off <<= 1) s += __shfl_xor(s, off, 64);
    float r = e / s;
    if (!last) {
        float rm = r;
#pragma unroll
        for (int off = 1; off < 64; off <<= 1) rm = fmaxf(rm, __shfl_xor(rm, off, 64));
        r = r / (rm + EPSF);
    }
    return r;
}

__global__ __launch_bounds__(1024, 4)
void attn_fused(const float* __restrict__ x,
                const float* __restrict__ fcW, const float* __restrict__ fcb,
                const float* __restrict__ p1W, const float* __restrict__ p1b,
                const float* __restrict__ p1s, const float* __restrict__ p1t,
                const float* __restrict__ p2W, const float* __restrict__ p2b,
                const float* __restrict__ p2s, const float* __restrict__ p2t,
                const float* __restrict__ oW,  const float* __restrict__ ob,
                const float* __restrict__ os,  const float* __restrict__ ot,
                float* __restrict__ out)
{
    __shared__ float pL[A * PAD];
    __shared__ float qL[A * PAD];
    __shared__ float mbuf[A];
    __shared__ float v1buf[A], v2buf[A];

    const int tid = threadIdx.x, lane = tid & 63, wv = tid >> 6;
    const int n = blockIdx.x;
    const int row0 = wv * 4;
    const int i = tid >> 4, j = (tid & 15) * 4;   // this thread's h elements: (i, j..j+3)

    // ---- load x once; stays in registers for the whole kernel ----
    const float4* x0v = (const float4*)(x + (size_t)n * 2 * A * A);
    const float4* x1v = x0v + (A * A / 4);
    const float4 a = x0v[tid];
    const float4 c = x1v[tid];
    const float w00 = fcW[0], w01 = fcW[1], w10 = fcW[2], w11 = fcW[3];
    const float b0 = fcb[0], b1 = fcb[1];

    // h channel 0 (used by stages B and D) and channel 1 (stage C), registers:
    const float h0v[4] = { fmaxf(0.f, w00 * a.x + w01 * c.x + b0),
                           fmaxf(0.f, w00 * a.y + w01 * c.y + b0),
                           fmaxf(0.f, w00 * a.z + w01 * c.z + b0),
                           fmaxf(0.f, w00 * a.w + w01 * c.w + b0) };
    const float h1v[4] = { fmaxf(0.f, w10 * a.x + w11 * c.x + b1),
                           fmaxf(0.f, w10 * a.y + w11 * c.y + b1),
                           fmaxf(0.f, w10 * a.z + w11 * c.z + b1),
                           fmaxf(0.f, w10 * a.w + w11 * c.w + b1) };

    // ======== stage B: X = h0 (row-major) ========
    {
        const float W0 = p1W[0], W1 = p1W[1], bb = p1b[0];
#pragma unroll
        for (int t = 0; t < 4; ++t) {
            pL[i * PAD + j + t] = ex2(-L2E * (W0 * h0v[t] + bb));
            qL[i * PAD + j + t] = ex2(-L2E * (W1 * h0v[t]));
        }
    }
    __syncthreads();
    att4(pL + lane * PAD, qL + lane * PAD, row0, lane, mbuf);
    __syncthreads();
    if (wv == 0) v1buf[lane] = softmax64(mbuf[lane], p1s[0], p1t[0], false);
    __syncthreads();

    // ======== stage C: X[r][k] = h1[k][r] * v1[k]  (transposed store) ========
    {
        const float W0 = p2W[0], W1 = p2W[1], bb = p2b[0];
        const float sc = v1buf[i];
#pragma unroll
        for (int t = 0; t < 4; ++t) {
            float hv = h1v[t] * sc;
            pL[(j + t) * PAD + i] = ex2(-L2E * (W0 * hv + bb));
            qL[(j + t) * PAD + i] = ex2(-L2E * (W1 * hv));
        }
    }
    __syncthreads();
    att4(pL + lane * PAD, qL + lane * PAD, row0, lane, mbuf);
    __syncthreads();
    if (wv == 0) v2buf[lane] = softmax64(mbuf[lane], p2s[0], p2t[0], false);
    __syncthreads();

    // ======== stage D: X = h0 * v1[i] * v2[j] (row-major) ========
    {
        const float W0 = oW[0], W1 = oW[1], bb = ob[0];
        const float sc = v1buf[i];
        const float4 v2q = *(const float4*)&v2buf[j];
        const float v2a[4] = { v2q.x, v2q.y, v2q.z, v2q.w };
#pragma unroll
        for (int t = 0; t < 4; ++t) {
            float hv = h0v[t] * sc * v2a[t];
            pL[i * PAD + j + t] = ex2(-L2E * (W0 * hv + bb));
            qL[i * PAD + j + t] = ex2(-L2E * (W1 * hv));
        }
    }
    __syncthreads();
    att4(pL + lane * PAD, qL + lane * PAD, row0, lane, mbuf);
    __syncthreads();

    // ======== final softmax (is_last) -> out ========
    if (wv == 0)
        out[(size_t)n * A + lane] = softmax64(mbuf[lane], os[0], ot[0], true);
}

extern "C" void kernel_launch(void* const* d_in, const int* in_sizes, int n_in,
                              void* d_out, int out_size, void* d_ws, size_t ws_size,
                              hipStream_t stream)
{
    (void)n_in; (void)out_size; (void)d_ws; (void)ws_size;
    const float* x   = (const float*)d_in[0];
    const float* fcW = (const float*)d_in[1];
    const float* fcb = (const float*)d_in[2];
    const float* p1W = (const float*)d_in[3];
    const float* p1b = (const float*)d_in[4];
    const float* p1s = (const float*)d_in[5];
    const float* p1t = (const float*)d_in[6];
    const float* p2W = (const float*)d_in[7];
    const float* p2b = (const float*)d_in[8];
    const float* p2s = (const float*)d_in[9];
    const float* p2t = (const float*)d_in[10];
    const float* oW  = (const float*)d_in[11];
    const float* ob  = (const float*)d_in[12];
    const float* os  = (const float*)d_in[13];
    const float* ot  = (const float*)d_in[14];
    float* out = (float*)d_out;

    const int N = in_sizes[0] / (2 * A * A);   // 128
    attn_fused<<<N, 1024, 0, stream>>>(x, fcW, fcb,
                                       p1W, p1b, p1s, p1t,
                                       p2W, p2b, p2s, p2t,
                                       oW, ob, os, ot, out);
}

// Round 6
// 105.462 us; speedup vs baseline: 1.1457x; 1.1457x over previous
//
#include <hip/hip_runtime.h>

// AttentionNet N=128, a1=a2=64, f=2 — R6: fused single launch, FULL chip.
// Grid 2N=256: two blocks per n, each reduces 32 att-rows/stage (2 rows/wave).
// Cross-block exchange of 32 m-scalars per stage via d_ws with device-scope
// atomics; values stored as m+2.0 (sign=0, exp=128) so 0xAA-poison and zeros
// are never mistaken for data -> no flags, no fences, no zeroing pass.
// Inner loop: p via strided LDS reads (PAD=65, 2-way = free), q via one
// register per row + v_readlane, then v_fma + v_rcp + add.

constexpr int A   = 64;
constexpr int PAD = 65;
constexpr float L2E  = 1.4426950408889634f;
constexpr float EPSF = 1e-6f;

__device__ __forceinline__ float bcast(float v, int srcLane) {
    return __int_as_float(__builtin_amdgcn_readlane(__float_as_int(v), srcLane));
}
__device__ __forceinline__ float rcpf(float v) { return __builtin_amdgcn_rcpf(v); }
__device__ __forceinline__ float ex2(float v)  { return __builtin_amdgcn_exp2f(v); }

// Reduce rows row0,row0+1 (lane <-> column j). lane0 writes LDS mbuf and the
// encoded global slot for the peer block.
__device__ __forceinline__ void att2q(const float* __restrict__ prow,
                                      const float* __restrict__ qL,
                                      int row0, int lane,
                                      float* __restrict__ mbuf,
                                      float* __restrict__ mg)   // [64] for this n,stage
{
    const float qreg0 = qL[row0 * PAD + lane];          // conflict-free row reads
    const float qreg1 = qL[(row0 + 1) * PAD + lane];
    float acc0 = 0.f, acc1 = 0.f;
#pragma unroll 1
    for (int c = 0; c < 4; ++c) {
        float pk[16];
#pragma unroll
        for (int t = 0; t < 16; ++t) pk[t] = prow[c * 16 + t];
#pragma unroll
        for (int t = 0; t < 16; ++t) {
            const int k = c * 16 + t;                   // uniform -> readlane ok
            float q0 = bcast(qreg0, k);
            float q1 = bcast(qreg1, k);
            acc0 += rcpf(fmaf(pk[t], q0, 1.0f));
            acc1 += rcpf(fmaf(pk[t], q1, 1.0f));
        }
    }
    float s0 = acc0, m0 = acc0, s1 = acc1, m1 = acc1;
#pragma unroll
    for (int off = 1; off < 64; off <<= 1) {
        s0 += __shfl_xor(s0, off, 64);
        m0 = fmaxf(m0, __shfl_xor(m0, off, 64));
        s1 += __shfl_xor(s1, off, 64);
        m1 = fmaxf(m1, __shfl_xor(m1, off, 64));
    }
    if (lane == 0) {
        // acc = 64*c: mean_j c = s/4096, max_j c = m/64.
        float v0 = (s0 * (1.0f / 4096.0f)) / (m0 * (1.0f / 64.0f) + EPSF);
        float v1 = (s1 * (1.0f / 4096.0f)) / (m1 * (1.0f / 64.0f) + EPSF);
        mbuf[row0]     = v0;
        mbuf[row0 + 1] = v1;
        __hip_atomic_store(mg + row0,     v0 + 2.0f, __ATOMIC_RELAXED, __HIP_MEMORY_SCOPE_AGENT);
        __hip_atomic_store(mg + row0 + 1, v1 + 2.0f, __ATOMIC_RELAXED, __HIP_MEMORY_SCOPE_AGENT);
    }
}

__device__ __forceinline__ float softmax64(float m, float sharp, float th, bool last)
{
    float v = fmaxf(0.f, m * sharp + th);
    float mx = v;
#pragma unroll
    for (int off = 1; off < 64; off <<= 1) mx = fmaxf(mx, __shfl_xor(mx, off, 64));
    float e = __expf(v - mx);
    float s = e;
#pragma unroll
    for (int off = 1; off < 64; off <<= 1) s += __shfl_xor(s, off, 64);
    float r = e / s;
    if (!last) {
        float rm = r;
#pragma unroll
        for (int off = 1; off < 64; off <<= 1) rm = fmaxf(rm, __shfl_xor(rm, off, 64));
        r = r / (rm + EPSF);
    }
    return r;
}

// Wave-0 only: gather full 64 m-values (own half from LDS, peer half via spin
// on encoded global slots), then softmax.
__device__ __forceinline__ float exch_soft(const float* __restrict__ mbuf,
                                           const float* __restrict__ mg,
                                           int half, int lane,
                                           float sharp, float th, bool last)
{
    float mv;
    if ((lane >> 5) == half) {
        mv = mbuf[lane];
    } else {
        const float* p = mg + lane;
        for (;;) {
            float f = __hip_atomic_load(p, __ATOMIC_RELAXED, __HIP_MEMORY_SCOPE_AGENT);
            unsigned u = __float_as_uint(f);
            if ((u >> 23) == 0x80u) { mv = f - 2.0f; break; }   // sign 0, exp 128
            __builtin_amdgcn_s_sleep(1);
        }
    }
    return softmax64(mv, sharp, th, last);
}

__global__ __launch_bounds__(1024, 2)
void attn_half(const float* __restrict__ x,
               const float* __restrict__ fcW, const float* __restrict__ fcb,
               const float* __restrict__ p1W, const float* __restrict__ p1b,
               const float* __restrict__ p1s, const float* __restrict__ p1t,
               const float* __restrict__ p2W, const float* __restrict__ p2b,
               const float* __restrict__ p2s, const float* __restrict__ p2t,
               const float* __restrict__ oW,  const float* __restrict__ ob,
               const float* __restrict__ os,  const float* __restrict__ ot,
               float* __restrict__ mglob,     // [N][3][64]
               float* __restrict__ out)
{
    __shared__ float pL[A * PAD];
    __shared__ float qL[A * PAD];
    __shared__ float mbuf[A];
    __shared__ float v1buf[A], v2buf[A];

    const int tid = threadIdx.x, lane = tid & 63, wv = tid >> 6;
    const int n = blockIdx.x >> 1, half = blockIdx.x & 1;
    const int row0 = half * 32 + wv * 2;
    const int i = tid >> 4, j = (tid & 15) * 4;
    float* mg = mglob + (size_t)n * 3 * A;

    // ---- x loaded once; h0/h1 live in registers ----
    const float4* x0v = (const float4*)(x + (size_t)n * 2 * A * A);
    const float4* x1v = x0v + (A * A / 4);
    const float4 a = x0v[tid];
    const float4 c = x1v[tid];
    const float w00 = fcW[0], w01 = fcW[1], w10 = fcW[2], w11 = fcW[3];
    const float b0 = fcb[0], b1 = fcb[1];
    const float h0v[4] = { fmaxf(0.f, w00 * a.x + w01 * c.x + b0),
                           fmaxf(0.f, w00 * a.y + w01 * c.y + b0),
                           fmaxf(0.f, w00 * a.z + w01 * c.z + b0),
                           fmaxf(0.f, w00 * a.w + w01 * c.w + b0) };
    const float h1v[4] = { fmaxf(0.f, w10 * a.x + w11 * c.x + b1),
                           fmaxf(0.f, w10 * a.y + w11 * c.y + b1),
                           fmaxf(0.f, w10 * a.z + w11 * c.z + b1),
                           fmaxf(0.f, w10 * a.w + w11 * c.w + b1) };

    // ======== stage B: X = h0 (row-major) ========
    {
        const float W0 = p1W[0], W1 = p1W[1], bb = p1b[0];
#pragma unroll
        for (int t = 0; t < 4; ++t) {
            pL[i * PAD + j + t] = ex2(-L2E * (W0 * h0v[t] + bb));
            qL[i * PAD + j + t] = ex2(-L2E * (W1 * h0v[t]));
        }
    }
    __syncthreads();
    att2q(pL + lane * PAD, qL, row0, lane, mbuf, mg);
    __syncthreads();
    if (wv == 0) v1buf[lane] = exch_soft(mbuf, mg, half, lane, p1s[0], p1t[0], false);
    __syncthreads();

    // ======== stage C: X[r][k] = h1[k][r] * v1[k] (transposed store) ========
    {
        const float W0 = p2W[0], W1 = p2W[1], bb = p2b[0];
        const float sc = v1buf[i];
#pragma unroll
        for (int t = 0; t < 4; ++t) {
            float hv = h1v[t] * sc;
            pL[(j + t) * PAD + i] = ex2(-L2E * (W0 * hv + bb));
            qL[(j + t) * PAD + i] = ex2(-L2E * (W1 * hv));
        }
    }
    __syncthreads();
    att2q(pL + lane * PAD, qL, row0, lane, mbuf, mg + A);
    __syncthreads();
    if (wv == 0) v2buf[lane] = exch_soft(mbuf, mg + A, half, lane, p2s[0], p2t[0], false);
    __syncthreads();

    // ======== stage D: X = h0 * v1[i] * v2[j] (row-major) ========
    {
        const float W0 = oW[0], W1 = oW[1], bb = ob[0];
        const float sc = v1buf[i];
        const float4 v2q = *(const float4*)&v2buf[j];
        const float v2a[4] = { v2q.x, v2q.y, v2q.z, v2q.w };
#pragma unroll
        for (int t = 0; t < 4; ++t) {
            float hv = h0v[t] * sc * v2a[t];
            pL[i * PAD + j + t] = ex2(-L2E * (W0 * hv + bb));
            qL[i * PAD + j + t] = ex2(-L2E * (W1 * hv));
        }
    }
    __syncthreads();
    att2q(pL + lane * PAD, qL, row0, lane, mbuf, mg + 2 * A);
    __syncthreads();

    // ======== final softmax (is_last); each block writes its 32 outputs ====
    if (wv == 0) {
        float r = exch_soft(mbuf, mg + 2 * A, half, lane, os[0], ot[0], true);
        if ((lane >> 5) == half) out[(size_t)n * A + lane] = r;
    }
}

extern "C" void kernel_launch(void* const* d_in, const int* in_sizes, int n_in,
                              void* d_out, int out_size, void* d_ws, size_t ws_size,
                              hipStream_t stream)
{
    (void)n_in; (void)out_size; (void)ws_size;
    const float* x   = (const float*)d_in[0];
    const float* fcW = (const float*)d_in[1];
    const float* fcb = (const float*)d_in[2];
    const float* p1W = (const float*)d_in[3];
    const float* p1b = (const float*)d_in[4];
    const float* p1s = (const float*)d_in[5];
    const float* p1t = (const float*)d_in[6];
    const float* p2W = (const float*)d_in[7];
    const float* p2b = (const float*)d_in[8];
    const float* p2s = (const float*)d_in[9];
    const float* p2t = (const float*)d_in[10];
    const float* oW  = (const float*)d_in[11];
    const float* ob  = (const float*)d_in[12];
    const float* os  = (const float*)d_in[13];
    const float* ot  = (const float*)d_in[14];
    float* out = (float*)d_out;

    const int N = in_sizes[0] / (2 * A * A);   // 128
    float* mglob = (float*)d_ws;               // [N][3][64]

    attn_half<<<2 * N, 1024, 0, stream>>>(x, fcW, fcb,
                                          p1W, p1b, p1s, p1t,
                                          p2W, p2b, p2s, p2t,
                                          oW, ob, os, ot, mglob, out);
}